// Round 2
// 320.137 us; speedup vs baseline: 1.0084x; 1.0084x over previous
//
#include <hip/hip_runtime.h>

// Autoregressive linear model via LTI decomposition + bf16 MFMA:
//   Araw[b,i,d] = sum_t y[b,t,d] * W[t-i,d]          (k_fused GEMM phase, MFMA)
//   h_d: impulse response of out_i = A_i + sum c_m out_{i-m}, c_m = W[2048-m]
//   out[b,i,d]  = sum_{m<=i} h_d[m]*Araw[b,i-m,d] + bias_d * cumsum(h_d)[i]
//
// R6: Toeplitz B fragments deduplicated (u = 2*kt - nt + 15, 142 frags/d,
// L2-resident).
// R8: recovery round. R7's two restructurings (k_prep merge, conv pairing)
// reverted after a correctness failure I could not localize by inspection.
// Kept ONLY the provably value-identical piece of R7: k_wt deleted, k_bfrag
// reads W[t*32+d] directly (bit-identical to Wt[d*2048+t]; W is 256 KB ->
// L2-resident). 6 -> 5 dispatches. Everything else is byte-for-byte R6.
//
// ws layout (bytes):
//   Af  [32][8][64][4][64][8] bf16 @ 0         (67,108,864)  A fragments
//   Bf  [32][142][64][8] bf16    @ 67108864    (4,653,056)   unique B frags
//   Og  [32][512][256] f32       @ 71761920    (16,777,216)  pre-transpose out
//   h_g [32][256] f32            @ 88539136    (32,768)
//   Hb  [32][256] f32            @ 88571904    (32,768)
// total ~84.7 MiB (ws is 512 MiB)

#define L_SZ   2048
#define D_SZ   32
#define NI_SZ  256
#define ST_A   324     // A_l row stride (f32): 64 front zero-pad + 256 + 4
#define NU     142     // unique B fragments per d

using frag_ab = __attribute__((ext_vector_type(8))) short;   // 8 bf16
using f32x4v  = __attribute__((ext_vector_type(4))) float;

__device__ inline ushort f2bf(float x) {
    uint32_t u = __float_as_uint(x);
    return (ushort)((u + 0x7fffu + ((u >> 16) & 1u)) >> 16);   // RTNE
}

// ---------------- k_trans: Y[b][t][d] f32 -> Af fragment blobs ----------------
// (unchanged: register-transpose + b128 swizzled LDS, conflict-free)
__global__ __launch_bounds__(256) void k_trans(const float* __restrict__ Y,
                                               ushort* __restrict__ Af) {
    __shared__ ushort sm[512 * 64];   // 64 KB
    int bq = blockIdx.x, tq = blockIdx.y;
    int b0 = bq * 16, t0 = tq * 64;
    int tid = threadIdx.x;
#pragma unroll
    for (int it = 0; it < 4; ++it) {
        int g = tid + it * 256;
        int dq = g & 7, bb = (g >> 3) & 15, tg = g >> 7;
        float4 v[8];
#pragma unroll
        for (int q = 0; q < 8; ++q)
            v[q] = *(const float4*)(Y + ((size_t)(b0 + bb) * L_SZ + t0 + tg * 8 + q) * D_SZ + dq * 4);
#pragma unroll
        for (int c = 0; c < 4; ++c) {
            int row = (dq * 4 + c) * 16 + bb;
            int key = (row ^ (row >> 3)) & 7;
            uint4 u;
            u.x = (uint)f2bf((&v[0].x)[c]) | ((uint)f2bf((&v[1].x)[c]) << 16);
            u.y = (uint)f2bf((&v[2].x)[c]) | ((uint)f2bf((&v[3].x)[c]) << 16);
            u.z = (uint)f2bf((&v[4].x)[c]) | ((uint)f2bf((&v[5].x)[c]) << 16);
            u.w = (uint)f2bf((&v[6].x)[c]) | ((uint)f2bf((&v[7].x)[c]) << 16);
            *(uint4*)&sm[row * 64 + ((tg ^ key) * 8)] = u;
        }
    }
    __syncthreads();
    int wv = tid >> 6, lane = tid & 63;
    int m = lane & 15, quad = lane >> 4;
    int bt = bq >> 2, mt = bq & 3;
#pragma unroll
    for (int j = 0; j < 16; ++j) {
        int fi = wv * 16 + j;              // 0..63 = 32 d x 2 ktl
        int d = fi >> 1, ktl = fi & 1;
        int row = d * 16 + m;
        int key = (row ^ (row >> 3)) & 7;
        int cn = ktl * 4 + quad;
        uint4 u = *(uint4*)&sm[row * 64 + ((cn ^ key) * 8)];
        int ktg = tq * 2 + ktl;
        size_t off = ((((size_t)(d * 8 + bt) * 64 + ktg) * 4 + mt) * 64 + lane) * 8;
        *(uint4*)(Af + off) = u;
    }
}

// ---------------- k_bfrag: UNIQUE Toeplitz B fragments ----------------
// u = 2*kt - nt + 15 in [0,142). Frag value(lane, j) = w[16*(u-15) +
// quad*8 + j - n], zero-clamped. One 64-thread block per (u, d).
// R8: reads W[t*32+d] directly (value-identical to the old Wt[d*2048+t]).
__global__ __launch_bounds__(64) void k_bfrag(const float* __restrict__ W,
                                              ushort* __restrict__ Bf) {
    __shared__ float wl[48];
    int u = blockIdx.x, d = blockIdx.y;
    int lane = threadIdx.x;
    int t0 = 16 * u - 255;                 // wl[s] = w[t0 + s], s in [0,48)
    if (lane < 48) {
        int t = t0 + lane;
        wl[lane] = (t >= 0 && t < L_SZ) ? W[(size_t)t * D_SZ + d] : 0.f;
    }
    __syncthreads();
    int n = lane & 15, quad = lane >> 4;
    int base = 15 + quad * 8 - n;          // in [0,39]; +j up to 46
    ushort s[8];
#pragma unroll
    for (int j = 0; j < 8; ++j) s[j] = f2bf(wl[base + j]);
    uint4 uu;
    uu.x = (uint)s[0] | ((uint)s[1] << 16);
    uu.y = (uint)s[2] | ((uint)s[3] << 16);
    uu.z = (uint)s[4] | ((uint)s[5] << 16);
    uu.w = (uint)s[6] | ((uint)s[7] << 16);
    *(uint4*)(Bf + ((size_t)(d * NU + u) * 64 + lane) * 8) = uu;
}

// ---------------- k1: impulse response h + Hb = bias*cumsum(h) ----------------
__global__ __launch_bounds__(64) void k1_h(const float* __restrict__ W,
                                           const float* __restrict__ bias,
                                           float* __restrict__ h_g,
                                           float* __restrict__ Hb) {
    int d = blockIdx.x;
    int lane = threadIdx.x;
    __shared__ float c_l[256];
    __shared__ float h_l[256];
#pragma unroll
    for (int k = 0; k < 4; ++k) {
        int m = lane + 64 * k;
        c_l[m] = (m >= 1) ? W[(L_SZ - m) * D_SZ + d] : 0.f;
    }
    __syncthreads();
    float s0 = 0.f, s1 = 0.f, s2 = 0.f, s3 = 0.f;
    for (int i = 0; i < 256; ++i) {
        int slot = i >> 6;
        float v = (slot == 0) ? s0 : (slot == 1) ? s1 : (slot == 2) ? s2 : s3;
        float hv = (i == 0) ? 1.f : __shfl(v, i & 63, 64);
        int j;
        j = lane;        if (j > i) s0 += c_l[j - i] * hv;
        j = lane + 64;   if (j > i) s1 += c_l[j - i] * hv;
        j = lane + 128;  if (j > i) s2 += c_l[j - i] * hv;
        j = lane + 192;  if (j > i) s3 += c_l[j - i] * hv;
    }
    float h0 = (lane == 0) ? 1.f : s0;
    h_g[d * 256 + lane]       = h0;
    h_g[d * 256 + lane + 64]  = s1;
    h_g[d * 256 + lane + 128] = s2;
    h_g[d * 256 + lane + 192] = s3;
    h_l[lane] = h0; h_l[lane + 64] = s1; h_l[lane + 128] = s2; h_l[lane + 192] = s3;
    __syncthreads();
    float bv = bias[d];
    float S[4] = {0.f, 0.f, 0.f, 0.f};
    for (int m = 0; m < 256; ++m) {
        float hm = h_l[m];
#pragma unroll
        for (int k = 0; k < 4; ++k)
            if (m <= lane + 64 * k) S[k] += hm;
    }
#pragma unroll
    for (int k = 0; k < 4; ++k)
        Hb[d * 256 + lane + 64 * k] = bv * S[k];
}

// ---------------- k_fused: GEMM (MFMA) + IIR conv, one block per (d, 32b) ---
// grid 512: d = (idx&7)*4 + ((idx>>3)&3)  [XCD-swizzle: same-d -> same XCD],
// bt2 = idx>>5. B frags via dedup index u = 2*ktl - nt + 15 (L2-resident).
__global__ __launch_bounds__(256, 2) void k_fused(const ushort* __restrict__ Af,
                                                  const ushort* __restrict__ Bf,
                                                  const float* __restrict__ h_g,
                                                  const float* __restrict__ Hb,
                                                  float* __restrict__ Og) {
    __shared__ float A_l[32 * ST_A];   // 41.5 KB
    __shared__ float h_l[256];
    __shared__ float hb_l[256];
    int idx = blockIdx.x;
    int d   = (idx & 7) * 4 + ((idx >> 3) & 3);
    int bt2 = idx >> 5;                 // 0..15
    int bt  = bt2 >> 1, msel = (bt2 & 1) * 2;
    int tid = threadIdx.x, w = tid >> 6, lane = tid & 63;
    int m = lane & 15, quad = lane >> 4;

    h_l[tid]  = h_g[d * 256 + tid];
    hb_l[tid] = Hb[d * 256 + tid];
    {
        int r = tid >> 3, c = (tid & 7) * 8;
#pragma unroll
        for (int k = 0; k < 8; ++k) A_l[r * ST_A + c + k] = 0.f;
    }

    const ushort* Ap = Af + ((size_t)(d * 8 + bt) * 256 + msel) * 512 + (size_t)lane * 8;
    const ushort* Bq = Bf + ((size_t)(d * NU + 15 - w * 4)) * 512 + (size_t)lane * 8;

    f32x4v acc[2][4];
#pragma unroll
    for (int mi = 0; mi < 2; ++mi)
#pragma unroll
        for (int nt = 0; nt < 4; ++nt) acc[mi][nt] = (f32x4v){0.f, 0.f, 0.f, 0.f};

    frag_ab a[4][2], bb[4][4];
#define LOADG(s, ktl) { _Pragma("unroll") for (int mi = 0; mi < 2; ++mi) \
        a[s][mi] = *(const frag_ab*)(Ap + (size_t)((ktl) * 4 + mi) * 512); \
    _Pragma("unroll") for (int nt = 0; nt < 4; ++nt) \
        bb[s][nt] = *(const frag_ab*)(Bq + ((ptrdiff_t)(2 * (ktl)) - nt) * 512); }
#define MFMA_G(s) { _Pragma("unroll") for (int mi = 0; mi < 2; ++mi) \
        _Pragma("unroll") for (int nt = 0; nt < 4; ++nt) \
        acc[mi][nt] = __builtin_amdgcn_mfma_f32_16x16x32_bf16(a[s][mi], bb[s][nt], acc[mi][nt], 0, 0, 0); }

#pragma unroll
    for (int pf = 0; pf < 4; ++pf) LOADG(pf, pf);
#pragma unroll 1
    for (int kt4 = 0; kt4 < 15; ++kt4) {
#pragma unroll
        for (int s = 0; s < 4; ++s) {
            MFMA_G(s);
            LOADG(s, kt4 * 4 + s + 4);
        }
    }
#pragma unroll
    for (int s = 0; s < 4; ++s) MFMA_G(s);
#undef LOADG
#undef MFMA_G

    // acc -> LDS: b_local = mi*16+quad*4+r, i = w*64+nt*16+m
#pragma unroll
    for (int mi = 0; mi < 2; ++mi)
#pragma unroll
        for (int nt = 0; nt < 4; ++nt)
#pragma unroll
            for (int r = 0; r < 4; ++r)
                A_l[(mi * 16 + quad * 4 + r) * ST_A + 64 + w * 64 + nt * 16 + m] =
                    acc[mi][nt][r];
    __syncthreads();

    // conv: lane owns row b_l = lane&31; ig = w*2 + (lane>>5) + 8k.
    int b_l = lane & 31;
    int half = lane >> 5;
    size_t obase = ((size_t)d * 512 + bt2 * 32 + b_l) * 256;
#pragma unroll 1
    for (int k = 0; k < 2; ++k) {
        int ig = w * 2 + half + 8 * k;
        int i0 = ig * 16;
        float c16[16];
#pragma unroll
        for (int ii = 0; ii < 16; ++ii) c16[ii] = 0.f;
        float w24[24];
#pragma unroll
        for (int j6 = 0; j6 < 6; ++j6)
            *(float4*)&w24[j6 * 4] = *(float4*)&A_l[b_l * ST_A + i0 + 56 + j6 * 4];
        int P = 4 * w + 16 * k + 4;        // wave-uniform; overrun masked by pad
#pragma unroll 1
        for (int p = 0; p < P; ++p) {
            float4 h0 = *(float4*)&h_l[p * 8];
            float4 h1 = *(float4*)&h_l[p * 8 + 4];
            float hv[8] = {h0.x, h0.y, h0.z, h0.w, h1.x, h1.y, h1.z, h1.w};
#pragma unroll
            for (int q = 0; q < 8; ++q)
#pragma unroll
                for (int ii = 0; ii < 16; ++ii)
                    c16[ii] += hv[q] * w24[ii + 8 - q];
#pragma unroll
            for (int j = 23; j >= 8; --j) w24[j] = w24[j - 8];
            if (p + 1 < P) {
                int nb = b_l * ST_A + i0 + 48 - p * 8;   // >= 32: in-bounds
                *(float4*)&w24[0] = *(float4*)&A_l[nb];
                *(float4*)&w24[4] = *(float4*)&A_l[nb + 4];
            }
        }
#pragma unroll
        for (int j4 = 0; j4 < 4; ++j4) {
            float4 o;
            o.x = c16[j4 * 4 + 0] + hb_l[i0 + j4 * 4 + 0];
            o.y = c16[j4 * 4 + 1] + hb_l[i0 + j4 * 4 + 1];
            o.z = c16[j4 * 4 + 2] + hb_l[i0 + j4 * 4 + 2];
            o.w = c16[j4 * 4 + 3] + hb_l[i0 + j4 * 4 + 3];
            *(float4*)(Og + obase + i0 + j4 * 4) = o;
        }
    }
}

// ---------------- k_outT: Og[d][b][i] -> out[b][i][d] ----------------
__global__ __launch_bounds__(256) void k_outT(const float* __restrict__ Og,
                                              float* __restrict__ out) {
    __shared__ float sm[32 * 260];   // 33.3 KB
    int b = blockIdx.x;
    int tid = threadIdx.x;
#pragma unroll
    for (int it = 0; it < 8; ++it) {
        int lin = tid + it * 256;          // 0..2047 = 32 d x 64 iq
        int iq = lin & 63, d = lin >> 6;
        float4 v = *(const float4*)(Og + ((size_t)d * 512 + b) * 256 + iq * 4);
        *(float4*)&sm[d * 260 + iq * 4] = v;
    }
    __syncthreads();
#pragma unroll
    for (int it = 0; it < 8; ++it) {
        int lin = tid + it * 256;          // 0..2047 = 8 dq x 256 i
        int dq = lin & 7, i = lin >> 3;
        float4 o;
        o.x = sm[(dq * 4 + 0) * 260 + i];
        o.y = sm[(dq * 4 + 1) * 260 + i];
        o.z = sm[(dq * 4 + 2) * 260 + i];
        o.w = sm[(dq * 4 + 3) * 260 + i];
        *(float4*)(out + ((size_t)b * 256 + i) * 32 + dq * 4) = o;
    }
}

extern "C" void kernel_launch(void* const* d_in, const int* in_sizes, int n_in,
                              void* d_out, int out_size, void* d_ws, size_t ws_size,
                              hipStream_t stream) {
    const float* y_c  = (const float*)d_in[0];   // [512][2048][32]
    const float* W    = (const float*)d_in[1];   // [2048][32]
    const float* bias = (const float*)d_in[2];   // [32]
    float* out = (float*)d_out;                  // [512][256][32]

    char* ws = (char*)d_ws;
    ushort* Af  = (ushort*)(ws);
    ushort* Bf  = (ushort*)(ws + 67108864);
    float*  Og  = (float*) (ws + 71761920);      // [32][512][256]
    float*  h_g = (float*) (ws + 88539136);
    float*  Hb  = (float*) (ws + 88571904);

    k_bfrag<<<dim3(NU, 32), 64, 0, stream>>>(W, Bf);
    k1_h   <<<32, 64, 0, stream>>>(W, bias, h_g, Hb);
    k_trans<<<dim3(32, 32), 256, 0, stream>>>(y_c, Af);
    k_fused<<<512, 256, 0, stream>>>(Af, Bf, h_g, Hb, Og);
    k_outT <<<512, 256, 0, stream>>>(Og, out);
}